// Round 6
// baseline (209.375 us; speedup 1.0000x reference)
//
#include <hip/hip_runtime.h>

typedef unsigned int u32;
typedef unsigned short u16;
typedef __attribute__((ext_vector_type(8))) __bf16 bf16x8;
typedef __attribute__((ext_vector_type(4))) float f32x4;

#define N_CAP 10
#define D_CAP 16
#define NN 160
#define KK 2048
#define BM 64
#define NSTEPS 64           // K-steps of 32 floats
#define THREADS 704         // 10 compute waves + 1 producer wave
#define HAT_STRIDE 165      // odd stride -> conflict-free routing reads
#define BSTEP 20480         // bytes per K-step of Wpack: 4 v * 5 wjp * 64 lanes * 16 B
#define ATILE 8192          // one staged A step: 64 rows x 32 f32
#define NBUF 3              // ring depth (A and B)

// Pre-split W, DMA-friendly layout: 16 B record (s, v, wjp, lane) at
// Wpack_g[(((s*4 + v)*5 + wjp)*64 + lane) * 16].
// v: 0=bh0 1=bh1 2=bl0 3=bl1.  bh0[j] = hi(W[32s + 8*(lane>>4) + j][32wjp + (lane&15)]),
// bh1: col+16, bl*: truncated low parts. 1.31 MB total, L2/L3-resident.
__device__ __align__(16) unsigned char Wpack_g[NSTEPS * BSTEP];

__device__ __forceinline__ u32 pack_hi(float f0, float f1) {
  // single v_perm_b32: bytes [f1.b3 f1.b2 f0.b3 f0.b2]
  return __builtin_amdgcn_perm(__builtin_bit_cast(u32, f1),
                               __builtin_bit_cast(u32, f0), 0x07060302u);
}
__device__ __forceinline__ float hi_part(float f) {
  u32 u = __builtin_bit_cast(u32, f) & 0xFFFF0000u;
  return __builtin_bit_cast(float, u);
}
union U4B8 { uint4 u; bf16x8 b; };

__device__ __forceinline__ void split2(const float4& x, const float4& y,
                                       bf16x8& h, bf16x8& l) {
  U4B8 hh, ll;
  hh.u.x = pack_hi(x.x, x.y); hh.u.y = pack_hi(x.z, x.w);
  hh.u.z = pack_hi(y.x, y.y); hh.u.w = pack_hi(y.z, y.w);
  float l0 = x.x - hi_part(x.x), l1 = x.y - hi_part(x.y);
  float l2 = x.z - hi_part(x.z), l3 = x.w - hi_part(x.w);
  float l4 = y.x - hi_part(y.x), l5 = y.y - hi_part(y.y);
  float l6 = y.z - hi_part(y.z), l7 = y.w - hi_part(y.w);
  ll.u.x = pack_hi(l0, l1); ll.u.y = pack_hi(l2, l3);
  ll.u.z = pack_hi(l4, l5); ll.u.w = pack_hi(l6, l7);
  h = hh.b; l = ll.b;
}

__device__ __forceinline__ void mfma12(bf16x8 ah0, bf16x8 al0, bf16x8 ah1,
                                       bf16x8 al1, bf16x8 bh0, bf16x8 bh1,
                                       bf16x8 bl0, bf16x8 bl1, f32x4& a00,
                                       f32x4& a01, f32x4& a10, f32x4& a11) {
  a00 = __builtin_amdgcn_mfma_f32_16x16x32_bf16(ah0, bh0, a00, 0, 0, 0);
  a00 = __builtin_amdgcn_mfma_f32_16x16x32_bf16(ah0, bl0, a00, 0, 0, 0);
  a00 = __builtin_amdgcn_mfma_f32_16x16x32_bf16(al0, bh0, a00, 0, 0, 0);
  a01 = __builtin_amdgcn_mfma_f32_16x16x32_bf16(ah0, bh1, a01, 0, 0, 0);
  a01 = __builtin_amdgcn_mfma_f32_16x16x32_bf16(ah0, bl1, a01, 0, 0, 0);
  a01 = __builtin_amdgcn_mfma_f32_16x16x32_bf16(al0, bh1, a01, 0, 0, 0);
  a10 = __builtin_amdgcn_mfma_f32_16x16x32_bf16(ah1, bh0, a10, 0, 0, 0);
  a10 = __builtin_amdgcn_mfma_f32_16x16x32_bf16(ah1, bl0, a10, 0, 0, 0);
  a10 = __builtin_amdgcn_mfma_f32_16x16x32_bf16(al1, bh0, a10, 0, 0, 0);
  a11 = __builtin_amdgcn_mfma_f32_16x16x32_bf16(ah1, bh1, a11, 0, 0, 0);
  a11 = __builtin_amdgcn_mfma_f32_16x16x32_bf16(ah1, bl1, a11, 0, 0, 0);
  a11 = __builtin_amdgcn_mfma_f32_16x16x32_bf16(al1, bh1, a11, 0, 0, 0);
}

__global__ void pack_w(const float* __restrict__ W) {
  const int tid = blockIdx.x * 256 + threadIdx.x;   // one 16 B record per thread
  if (tid >= NSTEPS * 4 * 5 * 64) return;
  const int lane = tid & 63;
  const int rest = tid >> 6;
  const int wjp = rest % 5;
  const int rest2 = rest / 5;
  const int v = rest2 & 3;               // 0:bh0 1:bh1 2:bl0 3:bl1
  const int s = rest2 >> 2;
  const int col = 32 * wjp + 16 * (v & 1) + (lane & 15);
  const int kb = 32 * s + 8 * (lane >> 4);
  u32 r[4];
#pragma unroll
  for (int jj = 0; jj < 4; ++jj) {
    float x0 = W[(size_t)(kb + 2 * jj) * NN + col];
    float x1 = W[(size_t)(kb + 2 * jj + 1) * NN + col];
    if (v >= 2) { x0 -= hi_part(x0); x1 -= hi_part(x1); }
    r[jj] = pack_hi(x0, x1);
  }
  uint4 o; o.x = r[0]; o.y = r[1]; o.z = r[2]; o.w = r[3];
  *(uint4*)(Wpack_g + (size_t)tid * 16) = o;
}

// async global->LDS DMA, 16 B per lane; lds base must be wave-uniform
#define GLOAD(gp, lp) __builtin_amdgcn_global_load_lds( \
    (const __attribute__((address_space(1))) u32*)(gp), \
    (__attribute__((address_space(3))) u32*)(lp), 16, 0, 0)
#define BARRIER() asm volatile("s_barrier" ::: "memory")
#define LGKM0() asm volatile("s_waitcnt lgkmcnt(0)" ::: "memory")

__global__ __launch_bounds__(THREADS, 1) void capsule_fused(
    const float* __restrict__ X, float* __restrict__ out) {
  __shared__ __align__(16) char AsA[NBUF * ATILE];       // 24 KiB A ring
  __shared__ __align__(16) char AsB[NBUF * BSTEP];       // 60 KiB B ring
  __shared__ __align__(16) float hat[BM * HAT_STRIDE];   // 42.24 KiB

  const int t = threadIdx.x;
  const int rbase = blockIdx.x * BM;
  const int lane = t & 63;
  const int w = t >> 6;                  // wave 0..10

  if (w == 10) {
    // ================= producer wave =================
    const float* g0 = X + (size_t)(rbase + (lane >> 3)) * KK
                        + (size_t)(((lane & 7) ^ (lane >> 3)) * 4);
    const unsigned char* gw0 = Wpack_g + (size_t)lane * 16;
#define STAGE(S, BV) do {                                         \
    const float* ga_ = g0 + (size_t)(S) * 32;                     \
    char* la_ = AsA + (BV) * ATILE;                               \
    GLOAD(ga_,           la_);                                    \
    GLOAD(ga_ +  8 * KK, la_ + 1024);                             \
    GLOAD(ga_ + 16 * KK, la_ + 2048);                             \
    GLOAD(ga_ + 24 * KK, la_ + 3072);                             \
    GLOAD(ga_ + 32 * KK, la_ + 4096);                             \
    GLOAD(ga_ + 40 * KK, la_ + 5120);                             \
    GLOAD(ga_ + 48 * KK, la_ + 6144);                             \
    GLOAD(ga_ + 56 * KK, la_ + 7168);                             \
    const unsigned char* gw_ = gw0 + (size_t)(S) * BSTEP;         \
    char* lw_ = AsB + (BV) * BSTEP;                               \
    _Pragma("unroll")                                             \
    for (int c_ = 0; c_ < 20; ++c_)                               \
      GLOAD(gw_ + c_ * 1024, lw_ + c_ * 1024);                    \
  } while (0)
    STAGE(0, 0);
    STAGE(1, 1);
    asm volatile("s_waitcnt vmcnt(0)" ::: "memory");   // tiles 0,1 landed
    BARRIER();                                         // #1
    STAGE(2, 2);
    BARRIER();                                         // #2
#pragma unroll 1
    for (int i = 0; i < NSTEPS; ++i) {
      if (i + 3 < NSTEPS) {
        STAGE(i + 3, i % 3);                           // slot (i+3)%3 == i%3
        asm volatile("s_waitcnt vmcnt(28)" ::: "memory");  // tile i+2 landed
      } else {
        asm volatile("s_waitcnt vmcnt(0)" ::: "memory");
      }
      BARRIER();
    }
#undef STAGE
  } else {
    // ================= consumer waves =================
    // Software-pipelined: at iter i, ds_read tile i+1 into regs while
    // computing tile i from regs read last iter. Compiler-visible loads only.
    const int wip = (w >= 5) ? 1 : 0;      // row half
    const int wjp = w - 5 * wip;           // col group of 32
    const int l15 = lane & 15;
    const int q = lane >> 4;
    const int r0 = 32 * wip + l15;
    const int r1 = r0 + 16;
    const int c0 = 2 * q, c1 = 2 * q + 1;
    const int o00 = (r0 >> 3) * 1024 + (r0 & 7) * 128 + ((c0 ^ (r0 & 7)) << 4);
    const int o01 = (r0 >> 3) * 1024 + (r0 & 7) * 128 + ((c1 ^ (r0 & 7)) << 4);
    const int o10 = (r1 >> 3) * 1024 + (r1 & 7) * 128 + ((c0 ^ (r1 & 7)) << 4);
    const int o11 = (r1 >> 3) * 1024 + (r1 & 7) * 128 + ((c1 ^ (r1 & 7)) << 4);
    const int ob = wjp * 1024 + lane * 16;

    f32x4 acc00 = {0.f,0.f,0.f,0.f}, acc01 = {0.f,0.f,0.f,0.f};
    f32x4 acc10 = {0.f,0.f,0.f,0.f}, acc11 = {0.f,0.f,0.f,0.f};

    float4 A00a, A01a, A10a, A11a, A00b, A01b, A10b, A11b;
    bf16x8 Bh0a, Bh1a, Bl0a, Bl1a, Bh0b, Bh1b, Bl0b, Bl1b;

#define READSET(SFX, SLOT) do {                                   \
    const char* ca_ = AsA + (SLOT) * ATILE;                       \
    const char* cb_ = AsB + (SLOT) * BSTEP + ob;                  \
    A00##SFX = *(const float4*)(ca_ + o00);                       \
    A01##SFX = *(const float4*)(ca_ + o01);                       \
    A10##SFX = *(const float4*)(ca_ + o10);                       \
    A11##SFX = *(const float4*)(ca_ + o11);                       \
    Bh0##SFX = *(const bf16x8*)(cb_);                             \
    Bh1##SFX = *(const bf16x8*)(cb_ + 5120);                      \
    Bl0##SFX = *(const bf16x8*)(cb_ + 10240);                     \
    Bl1##SFX = *(const bf16x8*)(cb_ + 15360);                     \
  } while (0)

#define COMPUTE(SFX) do {                                         \
    bf16x8 ah0, al0, ah1, al1;                                    \
    split2(A00##SFX, A01##SFX, ah0, al0);                         \
    split2(A10##SFX, A11##SFX, ah1, al1);                         \
    __builtin_amdgcn_s_setprio(1);                                \
    mfma12(ah0, al0, ah1, al1, Bh0##SFX, Bh1##SFX, Bl0##SFX,      \
           Bl1##SFX, acc00, acc01, acc10, acc11);                 \
    __builtin_amdgcn_s_setprio(0);                                \
  } while (0)

    BARRIER();                              // #1: tiles 0,1 landed
    READSET(a, 0);                          // tile 0 -> set a
    LGKM0();
    BARRIER();                              // #2
    int ni = 1;                             // LDS slot of next tile to read
#pragma unroll 1
    for (int ii = 0; ii < NSTEPS / 2; ++ii) {
      // even iter i=2ii: read tile i+1 -> set b, compute set a (tile i)
      READSET(b, ni);
      ni = (ni == 2) ? 0 : ni + 1;
      COMPUTE(a);
      LGKM0();
      BARRIER();
      // odd iter i=2ii+1: read tile i+1 -> set a, compute set b
      if (ii != NSTEPS / 2 - 1) {
        READSET(a, ni);
        ni = (ni == 2) ? 0 : ni + 1;
      }
      COMPUTE(b);
      LGKM0();
      BARRIER();
    }
#undef READSET
#undef COMPUTE

    // write hat (separate LDS region; ring is dead)
#pragma unroll
    for (int r = 0; r < 4; ++r) {
      // C/D layout: col = lane&15, row = (lane>>4)*4 + reg
      const int rowb = 32 * wip + 4 * q + r;
      const int colb = 32 * wjp + l15;
      hat[rowb * HAT_STRIDE + colb]             = acc00[r];
      hat[rowb * HAT_STRIDE + colb + 16]        = acc01[r];
      hat[(rowb + 16) * HAT_STRIDE + colb]      = acc10[r];
      hat[(rowb + 16) * HAT_STRIDE + colb + 16] = acc11[r];
    }
  }
  __syncthreads();

  // ---- routing: 8 lanes per row, register-resident hat, shfl reductions ----
  if (t < BM * 8) {
    const int r = t >> 3;
    const int d0 = t & 7;
    float h0[N_CAP], h1[N_CAP];
#pragma unroll
    for (int n = 0; n < N_CAP; ++n) {
      h0[n] = hat[r * HAT_STRIDE + n * D_CAP + d0];
      h1[n] = hat[r * HAT_STRIDE + n * D_CAP + d0 + 8];
    }
    float bb[N_CAP];
#pragma unroll
    for (int n = 0; n < N_CAP; ++n) bb[n] = 0.f;
    float v0 = 0.f, v1 = 0.f;
#pragma unroll
    for (int it = 0; it < 3; ++it) {
      float mx = bb[0];
#pragma unroll
      for (int n = 1; n < N_CAP; ++n) mx = fmaxf(mx, bb[n]);
      float c[N_CAP], se = 0.f;
#pragma unroll
      for (int n = 0; n < N_CAP; ++n) { c[n] = __expf(bb[n] - mx); se += c[n]; }
      const float inv = 1.f / se;
      float s0 = 0.f, s1 = 0.f;
#pragma unroll
      for (int n = 0; n < N_CAP; ++n) { s0 += c[n] * h0[n]; s1 += c[n] * h1[n]; }
      s0 *= inv; s1 *= inv;
      float s2 = s0 * s0 + s1 * s1;
      s2 += __shfl_xor(s2, 1);
      s2 += __shfl_xor(s2, 2);
      s2 += __shfl_xor(s2, 4);
      const float scale = s2 / ((1.f + s2) * sqrtf(s2 + 1e-7f));
      v0 = scale * s0; v1 = scale * s1;
      if (it < 2) {
#pragma unroll
        for (int n = 0; n < N_CAP; ++n) {
          float dd = h0[n] * v0 + h1[n] * v1;
          dd += __shfl_xor(dd, 1);
          dd += __shfl_xor(dd, 2);
          dd += __shfl_xor(dd, 4);
          bb[n] += dd;
        }
      }
    }
    out[(size_t)(rbase + r) * D_CAP + d0] = v0;
    out[(size_t)(rbase + r) * D_CAP + d0 + 8] = v1;
  }
}

extern "C" void kernel_launch(void* const* d_in, const int* in_sizes, int n_in,
                              void* d_out, int out_size, void* d_ws, size_t ws_size,
                              hipStream_t stream) {
  const float* X = (const float*)d_in[0];   // inputs [16384][2048] f32
  const float* W = (const float*)d_in[1];   // kernel [2048][160] f32
  if (n_in >= 2 && in_sizes[0] == KK * NN) {  // defensive: identify by element count
    X = (const float*)d_in[1];
    W = (const float*)d_in[0];
  }
  (void)d_ws; (void)ws_size; (void)out_size;
  pack_w<<<(NSTEPS * 4 * 5 * 64 + 255) / 256, 256, 0, stream>>>(W);
  capsule_fused<<<16384 / BM, THREADS, 0, stream>>>(X, (float*)d_out);
}

// Round 7
// 202.112 us; speedup vs baseline: 1.0359x; 1.0359x over previous
//
#include <hip/hip_runtime.h>

typedef unsigned int u32;
typedef unsigned short u16;
typedef __attribute__((ext_vector_type(8))) __bf16 bf16x8;
typedef __attribute__((ext_vector_type(4))) float f32x4;

#define N_CAP 10
#define D_CAP 16
#define NN 160
#define KK 2048
#define BM 64
#define NSTEPS 64           // K-steps of 32 floats
#define THREADS 704         // 10 compute waves + 1 producer wave
#define HAT_STRIDE 165      // odd stride -> conflict-free routing reads
#define BSTEP 20480         // bytes per K-step of Wpack: 4 v * 5 wjp * 64 lanes * 16 B
#define ATILE 8192          // one staged A step: 64 rows x 32 f32
#define NBUF 4              // ring depth: slot for tile t is t&3.
// Depth-4 is the load-bearing change: slot (i+1)&3 is only overwritten in
// window i+2, so consumer ds_reads issued in window i need only complete
// before their USE in window i+1 (compiler's counted lgkm wait) -- no manual
// lgkmcnt(0) before the barrier, so the LDS drain overlaps barrier + next
// window instead of serializing inside the window.

// Pre-split W, DMA-friendly layout: 16 B record (s, v, wjp, lane) at
// Wpack_g[(((s*4 + v)*5 + wjp)*64 + lane) * 16].
// v: 0=bh0 1=bh1 2=bl0 3=bl1.  bh0[j] = hi(W[32s + 8*(lane>>4) + j][32wjp + (lane&15)]),
// bh1: col+16, bl*: truncated low parts. 1.31 MB total, L2/L3-resident.
__device__ __align__(16) unsigned char Wpack_g[NSTEPS * BSTEP];

__device__ __forceinline__ u32 pack_hi(float f0, float f1) {
  // single v_perm_b32: bytes [f1.b3 f1.b2 f0.b3 f0.b2]
  return __builtin_amdgcn_perm(__builtin_bit_cast(u32, f1),
                               __builtin_bit_cast(u32, f0), 0x07060302u);
}
__device__ __forceinline__ float hi_part(float f) {
  u32 u = __builtin_bit_cast(u32, f) & 0xFFFF0000u;
  return __builtin_bit_cast(float, u);
}
union U4B8 { uint4 u; bf16x8 b; };

__device__ __forceinline__ void split2(const float4& x, const float4& y,
                                       bf16x8& h, bf16x8& l) {
  U4B8 hh, ll;
  hh.u.x = pack_hi(x.x, x.y); hh.u.y = pack_hi(x.z, x.w);
  hh.u.z = pack_hi(y.x, y.y); hh.u.w = pack_hi(y.z, y.w);
  float l0 = x.x - hi_part(x.x), l1 = x.y - hi_part(x.y);
  float l2 = x.z - hi_part(x.z), l3 = x.w - hi_part(x.w);
  float l4 = y.x - hi_part(y.x), l5 = y.y - hi_part(y.y);
  float l6 = y.z - hi_part(y.z), l7 = y.w - hi_part(y.w);
  ll.u.x = pack_hi(l0, l1); ll.u.y = pack_hi(l2, l3);
  ll.u.z = pack_hi(l4, l5); ll.u.w = pack_hi(l6, l7);
  h = hh.b; l = ll.b;
}

__device__ __forceinline__ void mfma12(bf16x8 ah0, bf16x8 al0, bf16x8 ah1,
                                       bf16x8 al1, bf16x8 bh0, bf16x8 bh1,
                                       bf16x8 bl0, bf16x8 bl1, f32x4& a00,
                                       f32x4& a01, f32x4& a10, f32x4& a11) {
  a00 = __builtin_amdgcn_mfma_f32_16x16x32_bf16(ah0, bh0, a00, 0, 0, 0);
  a00 = __builtin_amdgcn_mfma_f32_16x16x32_bf16(ah0, bl0, a00, 0, 0, 0);
  a00 = __builtin_amdgcn_mfma_f32_16x16x32_bf16(al0, bh0, a00, 0, 0, 0);
  a01 = __builtin_amdgcn_mfma_f32_16x16x32_bf16(ah0, bh1, a01, 0, 0, 0);
  a01 = __builtin_amdgcn_mfma_f32_16x16x32_bf16(ah0, bl1, a01, 0, 0, 0);
  a01 = __builtin_amdgcn_mfma_f32_16x16x32_bf16(al0, bh1, a01, 0, 0, 0);
  a10 = __builtin_amdgcn_mfma_f32_16x16x32_bf16(ah1, bh0, a10, 0, 0, 0);
  a10 = __builtin_amdgcn_mfma_f32_16x16x32_bf16(ah1, bl0, a10, 0, 0, 0);
  a10 = __builtin_amdgcn_mfma_f32_16x16x32_bf16(al1, bh0, a10, 0, 0, 0);
  a11 = __builtin_amdgcn_mfma_f32_16x16x32_bf16(ah1, bh1, a11, 0, 0, 0);
  a11 = __builtin_amdgcn_mfma_f32_16x16x32_bf16(ah1, bl1, a11, 0, 0, 0);
  a11 = __builtin_amdgcn_mfma_f32_16x16x32_bf16(al1, bh1, a11, 0, 0, 0);
}

__global__ void pack_w(const float* __restrict__ W) {
  const int tid = blockIdx.x * 256 + threadIdx.x;   // one 16 B record per thread
  if (tid >= NSTEPS * 4 * 5 * 64) return;
  const int lane = tid & 63;
  const int rest = tid >> 6;
  const int wjp = rest % 5;
  const int rest2 = rest / 5;
  const int v = rest2 & 3;               // 0:bh0 1:bh1 2:bl0 3:bl1
  const int s = rest2 >> 2;
  const int col = 32 * wjp + 16 * (v & 1) + (lane & 15);
  const int kb = 32 * s + 8 * (lane >> 4);
  u32 r[4];
#pragma unroll
  for (int jj = 0; jj < 4; ++jj) {
    float x0 = W[(size_t)(kb + 2 * jj) * NN + col];
    float x1 = W[(size_t)(kb + 2 * jj + 1) * NN + col];
    if (v >= 2) { x0 -= hi_part(x0); x1 -= hi_part(x1); }
    r[jj] = pack_hi(x0, x1);
  }
  uint4 o; o.x = r[0]; o.y = r[1]; o.z = r[2]; o.w = r[3];
  *(uint4*)(Wpack_g + (size_t)tid * 16) = o;
}

// async global->LDS DMA, 16 B per lane; lds base must be wave-uniform
#define GLOAD(gp, lp) __builtin_amdgcn_global_load_lds( \
    (const __attribute__((address_space(1))) u32*)(gp), \
    (__attribute__((address_space(3))) u32*)(lp), 16, 0, 0)
#define BARRIER() asm volatile("s_barrier" ::: "memory")

__global__ __launch_bounds__(THREADS, 1) void capsule_fused(
    const float* __restrict__ X, float* __restrict__ out) {
  __shared__ __align__(16) char AsA[NBUF * ATILE];       // 32 KiB A ring
  __shared__ __align__(16) char AsB[NBUF * BSTEP];       // 80 KiB B ring
  __shared__ __align__(16) float hat[BM * HAT_STRIDE];   // 42.24 KiB
  // total 156,928 B < 160 KiB -> 1 block/CU (grid = 256 = #CUs)

  const int t = threadIdx.x;
  const int rbase = blockIdx.x * BM;
  const int lane = t & 63;
  const int w = t >> 6;                  // wave 0..10

  if (w == 10) {
    // ================= producer wave =================
    const float* g0 = X + (size_t)(rbase + (lane >> 3)) * KK
                        + (size_t)(((lane & 7) ^ (lane >> 3)) * 4);
    const unsigned char* gw0 = Wpack_g + (size_t)lane * 16;
#define STAGE(S, BV) do {                                         \
    const float* ga_ = g0 + (size_t)(S) * 32;                     \
    char* la_ = AsA + (BV) * ATILE;                               \
    GLOAD(ga_,           la_);                                    \
    GLOAD(ga_ +  8 * KK, la_ + 1024);                             \
    GLOAD(ga_ + 16 * KK, la_ + 2048);                             \
    GLOAD(ga_ + 24 * KK, la_ + 3072);                             \
    GLOAD(ga_ + 32 * KK, la_ + 4096);                             \
    GLOAD(ga_ + 40 * KK, la_ + 5120);                             \
    GLOAD(ga_ + 48 * KK, la_ + 6144);                             \
    GLOAD(ga_ + 56 * KK, la_ + 7168);                             \
    const unsigned char* gw_ = gw0 + (size_t)(S) * BSTEP;         \
    char* lw_ = AsB + (BV) * BSTEP;                               \
    _Pragma("unroll")                                             \
    for (int c_ = 0; c_ < 20; ++c_)                               \
      GLOAD(gw_ + c_ * 1024, lw_ + c_ * 1024);                    \
  } while (0)
    STAGE(0, 0);
    STAGE(1, 1);
    asm volatile("s_waitcnt vmcnt(0)" ::: "memory");   // tiles 0,1 landed
    BARRIER();                                         // #1
    STAGE(2, 2);
    BARRIER();                                         // #2
#pragma unroll 1
    for (int i = 0; i < NSTEPS; ++i) {
      if (i + 3 < NSTEPS) {
        STAGE(i + 3, (i + 3) & 3);
        asm volatile("s_waitcnt vmcnt(28)" ::: "memory");  // tile i+2 landed
      } else {
        asm volatile("s_waitcnt vmcnt(0)" ::: "memory");
      }
      BARRIER();
    }
#undef STAGE
  } else {
    // ================= consumer waves =================
    // Pipelined LDS->reg: window i issues reads of tile i+1, computes tile i.
    // No manual lgkm waits: the compiler emits a counted lgkmcnt before the
    // first use (next window), letting the drain cross the barrier. Depth-4
    // ring makes that safe (slot not overwritten until window i+2).
    const int wip = (w >= 5) ? 1 : 0;      // row half
    const int wjp = w - 5 * wip;           // col group of 32
    const int l15 = lane & 15;
    const int q = lane >> 4;
    const int r0 = 32 * wip + l15;
    const int r1 = r0 + 16;
    const int c0 = 2 * q, c1 = 2 * q + 1;
    const int o00 = (r0 >> 3) * 1024 + (r0 & 7) * 128 + ((c0 ^ (r0 & 7)) << 4);
    const int o01 = (r0 >> 3) * 1024 + (r0 & 7) * 128 + ((c1 ^ (r0 & 7)) << 4);
    const int o10 = (r1 >> 3) * 1024 + (r1 & 7) * 128 + ((c0 ^ (r1 & 7)) << 4);
    const int o11 = (r1 >> 3) * 1024 + (r1 & 7) * 128 + ((c1 ^ (r1 & 7)) << 4);
    const int ob = wjp * 1024 + lane * 16;

    f32x4 acc00 = {0.f,0.f,0.f,0.f}, acc01 = {0.f,0.f,0.f,0.f};
    f32x4 acc10 = {0.f,0.f,0.f,0.f}, acc11 = {0.f,0.f,0.f,0.f};

    float4 A00a, A01a, A10a, A11a, A00b, A01b, A10b, A11b;
    bf16x8 Bh0a, Bh1a, Bl0a, Bl1a, Bh0b, Bh1b, Bl0b, Bl1b;

#define READSET(SFX, SLOT) do {                                   \
    const char* ca_ = AsA + (SLOT) * ATILE;                       \
    const char* cb_ = AsB + (SLOT) * BSTEP + ob;                  \
    A00##SFX = *(const float4*)(ca_ + o00);                       \
    A01##SFX = *(const float4*)(ca_ + o01);                       \
    A10##SFX = *(const float4*)(ca_ + o10);                       \
    A11##SFX = *(const float4*)(ca_ + o11);                       \
    Bh0##SFX = *(const bf16x8*)(cb_);                             \
    Bh1##SFX = *(const bf16x8*)(cb_ + 5120);                      \
    Bl0##SFX = *(const bf16x8*)(cb_ + 10240);                     \
    Bl1##SFX = *(const bf16x8*)(cb_ + 15360);                     \
  } while (0)

#define COMPUTE(SFX) do {                                         \
    bf16x8 ah0, al0, ah1, al1;                                    \
    split2(A00##SFX, A01##SFX, ah0, al0);                         \
    split2(A10##SFX, A11##SFX, ah1, al1);                         \
    __builtin_amdgcn_s_setprio(1);                                \
    mfma12(ah0, al0, ah1, al1, Bh0##SFX, Bh1##SFX, Bl0##SFX,      \
           Bl1##SFX, acc00, acc01, acc10, acc11);                 \
    __builtin_amdgcn_s_setprio(0);                                \
  } while (0)

    BARRIER();                              // #1: tiles 0,1 landed
    READSET(a, 0);                          // tile 0 -> set a
    BARRIER();                              // #2
    int ni = 1;                             // ring slot of next tile to read
#pragma unroll 1
    for (int ii = 0; ii < NSTEPS / 2; ++ii) {
      // even window i=2ii: read tile i+1 -> set b, compute set a (tile i)
      READSET(b, ni);
      ni = (ni + 1) & 3;
      COMPUTE(a);
      BARRIER();
      // odd window i=2ii+1: read tile i+1 -> set a, compute set b
      if (ii != NSTEPS / 2 - 1) {
        READSET(a, ni);
        ni = (ni + 1) & 3;
      }
      COMPUTE(b);
      BARRIER();
    }
#undef READSET
#undef COMPUTE

    // write hat (separate LDS region; ring is dead)
#pragma unroll
    for (int r = 0; r < 4; ++r) {
      // C/D layout: col = lane&15, row = (lane>>4)*4 + reg
      const int rowb = 32 * wip + 4 * q + r;
      const int colb = 32 * wjp + l15;
      hat[rowb * HAT_STRIDE + colb]             = acc00[r];
      hat[rowb * HAT_STRIDE + colb + 16]        = acc01[r];
      hat[(rowb + 16) * HAT_STRIDE + colb]      = acc10[r];
      hat[(rowb + 16) * HAT_STRIDE + colb + 16] = acc11[r];
    }
  }
  __syncthreads();

  // ---- routing: 8 lanes per row, register-resident hat, shfl reductions ----
  if (t < BM * 8) {
    const int r = t >> 3;
    const int d0 = t & 7;
    float h0[N_CAP], h1[N_CAP];
#pragma unroll
    for (int n = 0; n < N_CAP; ++n) {
      h0[n] = hat[r * HAT_STRIDE + n * D_CAP + d0];
      h1[n] = hat[r * HAT_STRIDE + n * D_CAP + d0 + 8];
    }
    float bb[N_CAP];
#pragma unroll
    for (int n = 0; n < N_CAP; ++n) bb[n] = 0.f;
    float v0 = 0.f, v1 = 0.f;
#pragma unroll
    for (int it = 0; it < 3; ++it) {
      float mx = bb[0];
#pragma unroll
      for (int n = 1; n < N_CAP; ++n) mx = fmaxf(mx, bb[n]);
      float c[N_CAP], se = 0.f;
#pragma unroll
      for (int n = 0; n < N_CAP; ++n) { c[n] = __expf(bb[n] - mx); se += c[n]; }
      const float inv = 1.f / se;
      float s0 = 0.f, s1 = 0.f;
#pragma unroll
      for (int n = 0; n < N_CAP; ++n) { s0 += c[n] * h0[n]; s1 += c[n] * h1[n]; }
      s0 *= inv; s1 *= inv;
      float s2 = s0 * s0 + s1 * s1;
      s2 += __shfl_xor(s2, 1);
      s2 += __shfl_xor(s2, 2);
      s2 += __shfl_xor(s2, 4);
      const float scale = s2 / ((1.f + s2) * sqrtf(s2 + 1e-7f));
      v0 = scale * s0; v1 = scale * s1;
      if (it < 2) {
#pragma unroll
        for (int n = 0; n < N_CAP; ++n) {
          float dd = h0[n] * v0 + h1[n] * v1;
          dd += __shfl_xor(dd, 1);
          dd += __shfl_xor(dd, 2);
          dd += __shfl_xor(dd, 4);
          bb[n] += dd;
        }
      }
    }
    out[(size_t)(rbase + r) * D_CAP + d0] = v0;
    out[(size_t)(rbase + r) * D_CAP + d0 + 8] = v1;
  }
}

extern "C" void kernel_launch(void* const* d_in, const int* in_sizes, int n_in,
                              void* d_out, int out_size, void* d_ws, size_t ws_size,
                              hipStream_t stream) {
  const float* X = (const float*)d_in[0];   // inputs [16384][2048] f32
  const float* W = (const float*)d_in[1];   // kernel [2048][160] f32
  if (n_in >= 2 && in_sizes[0] == KK * NN) {  // defensive: identify by element count
    X = (const float*)d_in[1];
    W = (const float*)d_in[0];
  }
  (void)d_ws; (void)ws_size; (void)out_size;
  pack_w<<<(NSTEPS * 4 * 5 * 64 + 255) / 256, 256, 0, stream>>>(W);
  capsule_fused<<<16384 / BM, THREADS, 0, stream>>>(X, (float*)d_out);
}